// Round 10
// baseline (48.338 us; speedup 1.0000x reference)
//
#include <hip/hip_runtime.h>
#include <math.h>

// Poisson MC estimator. R10: TRANSPOSED layout — one wave per query, lanes
// parallel over landmarks. R1-R9 post-mortems: all broadcast-LDS structures
// (R2/R4/R7/R9, three different tilings) land at 27-31us because
// v_pk_f32 is throughput-neutral (same FLOP/cy as scalar), v_rsq is
// quarter-rate, and the LDS broadcast / combine-kernel overheads trade
// against each other. This structure removes LDS entirely:
//  - landmark recs stream from global, perfectly coalesced dwordx4,
//    40KB working set (L1/L2-resident), VMEM pipe overlaps VALU
//  - no partials, no barriers, no combine kernel: each wave reduces its
//    5 sums with a 6-step __shfl_xor butterfly (crossbar, tail-only) and
//    writes its query's 4 outputs exactly once -> deterministic
//  - 0 LDS + ~30 VGPR -> 8 waves/SIMD (vs 4 before): rsq/VMEM latency
//    finally hidden under VALU issue.
// Per-pair math = R1/R2's silicon-proven scalar chain (no pk asm).

#define EPS2    1e-4f
#define INV_4PI 0.07957747154594767f

constexpr int M_LAND = 2048;
constexpr int ITERS  = M_LAND / 64;    // 32 landmarks-chunks per wave

// ---- pack kernel: rec[j] = (-2y0, -2y1, -2y2, ||y||^2 + eps^2) ----
__global__ void poisson_pack_kernel(const float* __restrict__ xl,
                                    float* __restrict__ rec)
{
    int j = blockIdx.x * 256 + threadIdx.x;
    if (j < M_LAND) {
        float l0 = xl[3*j], l1 = xl[3*j+1], l2 = xl[3*j+2];
        ((float4*)rec)[j] =
            make_float4(-2.0f*l0, -2.0f*l1, -2.0f*l2,
                        l0*l0 + l1*l1 + l2*l2 + EPS2);
    }
}

// ---- main kernel: 8 waves/block, one query per wave ----
template<bool PACKED>
__global__ __launch_bounds__(512)
void poisson_qwave_kernel(const float* __restrict__ xq,
                          const float* __restrict__ rec,   // packed recs (or xl raw)
                          const float* __restrict__ gl,
                          float* __restrict__ out, int B)
{
    const int lane = threadIdx.x & 63;
    const int wid  = __builtin_amdgcn_readfirstlane(threadIdx.x >> 6);
    const int q    = blockIdx.x * 8 + wid;
    if (q >= B) return;

    // wave-uniform query -> scalar loads
    const float q0 = xq[3*q], q1 = xq[3*q+1], q2 = xq[3*q+2];
    const float qe = q0*q0 + q1*q1 + q2*q2;

    float av = 0.f, ac = 0.f, ax = 0.f, ay = 0.f, az = 0.f;

#pragma unroll 4
    for (int it = 0; it < ITERS; ++it) {
        const int j = it * 64 + lane;
        float m0, m1, m2, ne;
        if (PACKED) {
            const float4 r = ((const float4*)rec)[j];   // coalesced dwordx4
            m0 = r.x; m1 = r.y; m2 = r.z; ne = r.w;
        } else {
            float l0 = rec[3*j], l1 = rec[3*j+1], l2 = rec[3*j+2];
            m0 = -2.0f*l0; m1 = -2.0f*l1; m2 = -2.0f*l2;
            ne = l0*l0 + l1*l1 + l2*l2 + EPS2;
        }
        const float g = gl[j];

        // t = qe + ||y||^2 + eps^2 - 2 q.y  == max(r2,0)+eps^2 after clamp
        float t = fmaf(m0, q0, fmaf(m1, q1, fmaf(m2, q2, qe + ne)));
        t = fmaxf(t, EPS2);
        float s  = __builtin_amdgcn_rsqf(t);
        float s3 = s * s * s;
        float c  = g * s3;

        av = fmaf(g, s, av);           // Σ g·s
        ac += c;                       // Σ c
        ax = fmaf(c, m0, ax);          // Σ c·(-2y0)
        ay = fmaf(c, m1, ay);
        az = fmaf(c, m2, az);
    }

    // ---- 64-lane butterfly reduction (crossbar, no LDS storage) ----
#pragma unroll
    for (int m = 1; m < 64; m <<= 1) {
        av += __shfl_xor(av, m, 64);
        ac += __shfl_xor(ac, m, 64);
        ax += __shfl_xor(ax, m, 64);
        ay += __shfl_xor(ay, m, 64);
        az += __shfl_xor(az, m, 64);
    }

    if (lane == 0) {
        const float k = INV_4PI / (float)M_LAND;
        out[q] = av * k;
        // grad_c = -k * (q_c*Σc - Σ c·y_c) = -k * (q_c*Σc + 0.5*Σ c·(-2y_c))
        out[B + 3*q + 0] = -k * fmaf(q0, ac, 0.5f * ax);
        out[B + 3*q + 1] = -k * fmaf(q1, ac, 0.5f * ay);
        out[B + 3*q + 2] = -k * fmaf(q2, ac, 0.5f * az);
    }
}

extern "C" void kernel_launch(void* const* d_in, const int* in_sizes, int n_in,
                              void* d_out, int out_size, void* d_ws, size_t ws_size,
                              hipStream_t stream)
{
    const float* xq = (const float*)d_in[0];   // (B,3)
    const float* xl = (const float*)d_in[1];   // (M,3)
    const float* gl = (const float*)d_in[2];   // (M,)
    float* out = (float*)d_out;

    const int B    = in_sizes[0] / 3;          // 32768
    const int grid = (B + 7) / 8;              // 8 queries (waves) per block

    if (ws_size >= (size_t)(M_LAND * 4 * sizeof(float))) {
        float* rec = (float*)d_ws;             // 32 KB packed landmark recs
        poisson_pack_kernel<<<(M_LAND + 255) / 256, 256, 0, stream>>>(xl, rec);
        poisson_qwave_kernel<true><<<grid, 512, 0, stream>>>(xq, rec, gl, out, B);
    } else {
        poisson_qwave_kernel<false><<<grid, 512, 0, stream>>>(xq, xl, gl, out, B);
    }
}

// Round 11
// 33.309 us; speedup vs baseline: 1.4512x; 1.4512x over previous
//
#include <hip/hip_runtime.h>
#include <math.h>

// Poisson MC estimator. R11: scalar-pipe supply, compiler-managed.
// Evidence: R10 counters show per-lane VMEM is L1-BW-bound (~33us); R2-R9
// show LDS broadcast costs ~12-16cy/read on the shared LDS pipe (~20-27us);
// pk-f32 is throughput-neutral. Remaining supply path: SMEM. R3 proved
// s_load correctness on silicon; its failure was hand-rolled serialization.
// Here the compiler generates the scalar loads: the per-wave slice pointer
// is uniform via readfirstlane -> LLVM uniformity analysis emits
// s_load_dwordx8 with batched waits (handles SMEM out-of-order returns).
// Main loop: 12 VALU + 1 rsq per pair, one SGPR operand per instr, zero
// LDS, zero VMEM. 1 query/lane, QPB=64, grid=512 (2 blocks/CU, 8 w/SIMD).
// Record: (m0,m1,m2, ne, h0,h1,h2, g) = (-2y, yy+eps^2, g*y, g).
// All plain HIP - no inline asm anywhere in the fast path.

#define EPS2    1e-4f
#define INV_4PI 0.07957747154594767f

constexpr int M_LAND = 2048;
constexpr int NW     = 16;                 // waves per block
constexpr int SLICE  = M_LAND / NW;        // 128 landmarks per wave
constexpr int QPB    = 64;                 // queries per block (1 per lane)

// ---- pack kernel ----
__global__ void poisson_pack_kernel(const float* __restrict__ xl,
                                    const float* __restrict__ gl,
                                    float* __restrict__ ws)
{
    int j = blockIdx.x * 256 + threadIdx.x;
    if (j < M_LAND) {
        float l0 = xl[3*j], l1 = xl[3*j+1], l2 = xl[3*j+2], g = gl[j];
        float* r = ws + 8*j;
        r[0] = -2.0f*l0;  r[1] = -2.0f*l1;  r[2] = -2.0f*l2;
        r[3] = l0*l0 + l1*l1 + l2*l2 + EPS2;
        r[4] = g*l0;      r[5] = g*l1;      r[6] = g*l2;      r[7] = g;
    }
}

// ---- main kernel: SGPR-supplied pairwise sums ----
__global__ __launch_bounds__(1024, 4)
void poisson_sgpr_kernel(const float* __restrict__ xq,
                         const float* __restrict__ rec,
                         float* __restrict__ out, int B)
{
    __shared__ float part[NW][QPB][5];     // 20 KB

    const int tid   = threadIdx.x;
    const int lane  = tid & 63;
    const int w     = tid >> 6;
    const int qbase = blockIdx.x * QPB;
    const int q     = qbase + lane;

    const float q0 = xq[3*q], q1 = xq[3*q+1], q2 = xq[3*q+2];
    const float qe = q0*q0 + q1*q1 + q2*q2;

    float av = 0.f, ac = 0.f, ax = 0.f, ay = 0.f, az = 0.f;

    // wave-uniform slice pointer: readfirstlane makes it provably uniform,
    // so the backend scalarizes the loads (s_load_dwordx8 batches).
    const int wu = __builtin_amdgcn_readfirstlane(w * SLICE);
    const float* __restrict__ lm = rec + (size_t)wu * 8;

#pragma unroll 4
    for (int i = 0; i < SLICE; ++i) {
        const float m0 = lm[8*i+0];        // SGPR (uniform)
        const float m1 = lm[8*i+1];
        const float m2 = lm[8*i+2];
        const float ne = lm[8*i+3];
        const float h0 = lm[8*i+4];
        const float h1 = lm[8*i+5];
        const float h2 = lm[8*i+6];
        const float g  = lm[8*i+7];

        // t = qe + ne - 2 q.y ; clamp == maximum(r2,0)+eps^2 exactly
        float t = fmaf(m0, q0, fmaf(m1, q1, fmaf(m2, q2, qe + ne)));
        t = fmaxf(t, EPS2);
        float s  = __builtin_amdgcn_rsqf(t);
        float s2 = s * s;
        float s3 = s2 * s;

        av = fmaf(g,  s,  av);             // Σ g·s
        ac = fmaf(g,  s3, ac);             // Σ c        (c = g·s³)
        ax = fmaf(s3, h0, ax);             // Σ c·y0     (h = g·y)
        ay = fmaf(s3, h1, ay);
        az = fmaf(s3, h2, az);
    }

    part[w][lane][0] = av;  part[w][lane][1] = ac;
    part[w][lane][2] = ax;  part[w][lane][3] = ay;  part[w][lane][4] = az;

    __syncthreads();

    // ---- reduce: 256 threads = 64 queries x 4 components ----
    if (tid < 256) {
        const int ql  = tid >> 2;
        const int cmp = tid & 3;
        const int qg  = qbase + ql;
        if (cmp == 0) {
            float sum = 0.f;
            #pragma unroll
            for (int ww = 0; ww < NW; ++ww) sum += part[ww][ql][0];
            out[qg] = sum * (INV_4PI / (float)M_LAND);
        } else {
            float sc = 0.f, sy = 0.f;
            #pragma unroll
            for (int ww = 0; ww < NW; ++ww) {
                sc += part[ww][ql][1];
                sy += part[ww][ql][1 + cmp];   // Σ c·y_c
            }
            const float qc = xq[3*qg + (cmp-1)];
            // grad_c = -inv4pi/M * (q_c·Σc - Σ c·y_c)
            out[B + 3*qg + (cmp-1)] =
                (-INV_4PI / (float)M_LAND) * fmaf(qc, sc, -sy);
        }
    }
}

// ======== fallback: R4 kernel verbatim (silicon-proven, 26.9us) ========
typedef float f32x2 __attribute__((ext_vector_type(2)));

#define PAIR_COMPUTE(Q0_, Q1_, Q2_, QE_, AV_, AC_, AX_, AY_, AZ_) do { \
    f32x2 T; \
    asm("v_pk_add_f32 %0, %1, %2 op_sel:[0,1] op_sel_hi:[1,1]\n\t" \
        "v_pk_fma_f32 %0, %2, %3, %0 op_sel:[0,0,0] op_sel_hi:[0,1,1]\n\t" \
        "v_pk_fma_f32 %0, %4, %5, %0 op_sel:[1,0,0] op_sel_hi:[1,1,1]\n\t" \
        "v_pk_fma_f32 %0, %4, %6, %0 op_sel:[0,0,0] op_sel_hi:[0,1,1]" \
        : "=&v"(T) \
        : "v"(QE_), "v"(P2W), "v"(Q2_), "v"(P01), "v"(Q1_), "v"(Q0_)); \
    float ta = fmaxf(T.x, EPS2); \
    float tb = fmaxf(T.y, EPS2); \
    f32x2 S = { __builtin_amdgcn_rsqf(ta), __builtin_amdgcn_rsqf(tb) }; \
    f32x2 S2, S3; \
    asm("v_pk_mul_f32 %0, %7, %7 op_sel:[0,0] op_sel_hi:[1,1]\n\t" \
        "v_pk_mul_f32 %1, %0, %7 op_sel:[0,0] op_sel_hi:[1,1]\n\t" \
        "v_pk_fma_f32 %2, %8, %7, %2 op_sel:[1,0,0] op_sel_hi:[1,1,1]\n\t" \
        "v_pk_fma_f32 %3, %8, %1, %3 op_sel:[1,0,0] op_sel_hi:[1,1,1]\n\t" \
        "v_pk_fma_f32 %4, %1, %9, %4 op_sel:[0,0,0] op_sel_hi:[1,0,1]\n\t" \
        "v_pk_fma_f32 %5, %1, %9, %5 op_sel:[0,1,0] op_sel_hi:[1,1,1]\n\t" \
        "v_pk_fma_f32 %6, %1, %8, %6 op_sel:[0,0,0] op_sel_hi:[1,0,1]" \
        : "=&v"(S2), "=&v"(S3), \
          "+v"(AV_), "+v"(AC_), "+v"(AX_), "+v"(AY_), "+v"(AZ_) \
        : "v"(S), "v"(G2G), "v"(G01)); \
} while (0)

constexpr int NW_F  = 16;
constexpr int SL_F  = M_LAND / NW_F;
constexpr int QPB_F = 128;

__global__ __launch_bounds__(1024, 4)
void poisson_pk_kernel(const float* __restrict__ xq,
                       const float* __restrict__ xl,
                       const float* __restrict__ gl,
                       float* __restrict__ out, int B)
{
    __shared__ float4 pack[M_LAND];
    __shared__ float4 gpack[M_LAND];
    __shared__ float  part[NW_F][QPB_F][5];

    const int tid = threadIdx.x;
    for (int j = tid; j < M_LAND; j += 1024) {
        float l0 = xl[3*j], l1 = xl[3*j+1], l2 = xl[3*j+2], g = gl[j];
        float n2 = l0*l0 + l1*l1 + l2*l2 + EPS2;
        pack[j]  = make_float4(-2.0f*l0, -2.0f*l1, -2.0f*l2, n2);
        gpack[j] = make_float4(-2.0f*g*l0, -2.0f*g*l1, -2.0f*g*l2, g);
    }
    const int lane = tid & 63, w = tid >> 6;
    const int qbase = blockIdx.x * QPB_F;
    const int qa = qbase + lane, qb = qbase + 64 + lane;
    const float a0 = xq[3*qa], a1 = xq[3*qa+1], a2 = xq[3*qa+2];
    const float b0 = xq[3*qb], b1 = xq[3*qb+1], b2 = xq[3*qb+2];
    f32x2 Q0 = {a0, b0}, Q1 = {a1, b1}, Q2 = {a2, b2};
    f32x2 QE = {a0*a0 + a1*a1 + a2*a2, b0*b0 + b1*b1 + b2*b2};
    f32x2 AV = {0,0}, AC = {0,0}, AX = {0,0}, AY = {0,0}, AZ = {0,0};
    __syncthreads();

    const int base = w * SL_F;
#pragma unroll 8
    for (int i = 0; i < SL_F; ++i) {
        const float4 p  = pack[base + i];
        const float4 gp = gpack[base + i];
        f32x2 P01 = {p.x,  p.y};
        f32x2 P2W = {p.z,  p.w};
        f32x2 G01 = {gp.x, gp.y};
        f32x2 G2G = {gp.z, gp.w};
        PAIR_COMPUTE(Q0, Q1, Q2, QE, AV, AC, AX, AY, AZ);
    }
    part[w][lane][0] = AV.x;  part[w][lane][1] = AC.x;
    part[w][lane][2] = AX.x;  part[w][lane][3] = AY.x;  part[w][lane][4] = AZ.x;
    part[w][lane+64][0] = AV.y;  part[w][lane+64][1] = AC.y;
    part[w][lane+64][2] = AX.y;  part[w][lane+64][3] = AY.y;  part[w][lane+64][4] = AZ.y;
    __syncthreads();
    if (tid < 512) {
        const int q = tid >> 2, cmp = tid & 3, qg = qbase + q;
        if (cmp == 0) {
            float s = 0.f;
            #pragma unroll
            for (int ww = 0; ww < NW_F; ++ww) s += part[ww][q][0];
            out[qg] = s * (INV_4PI / (float)M_LAND);
        } else {
            float sc = 0.f, sy = 0.f;
            #pragma unroll
            for (int ww = 0; ww < NW_F; ++ww) {
                sc += part[ww][q][1];
                sy += part[ww][q][1 + cmp];
            }
            const float qc = xq[3*qg + (cmp-1)];
            out[B + 3*qg + (cmp-1)] =
                (-INV_4PI / (float)M_LAND) * fmaf(qc, sc, 0.5f * sy);
        }
    }
}

extern "C" void kernel_launch(void* const* d_in, const int* in_sizes, int n_in,
                              void* d_out, int out_size, void* d_ws, size_t ws_size,
                              hipStream_t stream)
{
    const float* xq = (const float*)d_in[0];   // (B,3)
    const float* xl = (const float*)d_in[1];   // (M,3)
    const float* gl = (const float*)d_in[2];   // (M,)
    float* out = (float*)d_out;

    const int B = in_sizes[0] / 3;             // 32768

    if (ws_size >= (size_t)(M_LAND * 8 * sizeof(float)) && (B % QPB) == 0) {
        float* ws = (float*)d_ws;              // 64 KB packed records
        poisson_pack_kernel<<<(M_LAND + 255) / 256, 256, 0, stream>>>(xl, gl, ws);
        poisson_sgpr_kernel<<<B / QPB, 1024, 0, stream>>>(xq, ws, out, B);
    } else {
        poisson_pk_kernel<<<B / QPB_F, 1024, 0, stream>>>(xq, xl, gl, out, B);
    }
}

// Round 12
// 28.091 us; speedup vs baseline: 1.7208x; 1.1858x over previous
//
#include <hip/hip_runtime.h>
#include <math.h>

// Poisson MC estimator. R12: occupancy experiment — R4's silicon-proven
// kernel (asm FROZEN verbatim) at 8 waves/SIMD instead of 4.
// Model fit over R1-R11: VALU-pipe (pk + fmax + rsq-blocking) ~18-19us is
// the floor; the extra ~8us in every variant is supply latency that
// 4 waves/SIMD cannot hide (R1->R2: 2->4 waves gained 2.8us).
// msplit=2: grid = 256 qblocks x 2 M-halves = 512 x 1024thr = 2 blocks/CU
// = 32 waves/CU = 8/SIMD. LDS 72KB/block (2x72=144<=160 OK).
// launch_bounds(1024,8) caps VGPR at 64; unroll 2 keeps pressure low.
// Reads/CU and VALU totals IDENTICAL to R4 -> clean A/B on overlap.
// 2-way combine kernel (R9-proven pattern), fixed-order, deterministic.

#define EPS2    1e-4f
#define INV_4PI 0.07957747154594767f

constexpr int M_LAND = 2048;

typedef float f32x2 __attribute__((ext_vector_type(2)));

// ---- R4's silicon-validated pk compute, verbatim (DO NOT EDIT) ----
#define PAIR_COMPUTE(Q0_, Q1_, Q2_, QE_, AV_, AC_, AX_, AY_, AZ_) do { \
    f32x2 T; \
    asm("v_pk_add_f32 %0, %1, %2 op_sel:[0,1] op_sel_hi:[1,1]\n\t" \
        "v_pk_fma_f32 %0, %2, %3, %0 op_sel:[0,0,0] op_sel_hi:[0,1,1]\n\t" \
        "v_pk_fma_f32 %0, %4, %5, %0 op_sel:[1,0,0] op_sel_hi:[1,1,1]\n\t" \
        "v_pk_fma_f32 %0, %4, %6, %0 op_sel:[0,0,0] op_sel_hi:[0,1,1]" \
        : "=&v"(T) \
        : "v"(QE_), "v"(P2W), "v"(Q2_), "v"(P01), "v"(Q1_), "v"(Q0_)); \
    float ta = fmaxf(T.x, EPS2); \
    float tb = fmaxf(T.y, EPS2); \
    f32x2 S = { __builtin_amdgcn_rsqf(ta), __builtin_amdgcn_rsqf(tb) }; \
    f32x2 S2, S3; \
    asm("v_pk_mul_f32 %0, %7, %7 op_sel:[0,0] op_sel_hi:[1,1]\n\t" \
        "v_pk_mul_f32 %1, %0, %7 op_sel:[0,0] op_sel_hi:[1,1]\n\t" \
        "v_pk_fma_f32 %2, %8, %7, %2 op_sel:[1,0,0] op_sel_hi:[1,1,1]\n\t" \
        "v_pk_fma_f32 %3, %8, %1, %3 op_sel:[1,0,0] op_sel_hi:[1,1,1]\n\t" \
        "v_pk_fma_f32 %4, %1, %9, %4 op_sel:[0,0,0] op_sel_hi:[1,0,1]\n\t" \
        "v_pk_fma_f32 %5, %1, %9, %5 op_sel:[0,1,0] op_sel_hi:[1,1,1]\n\t" \
        "v_pk_fma_f32 %6, %1, %8, %6 op_sel:[0,0,0] op_sel_hi:[1,0,1]" \
        : "=&v"(S2), "=&v"(S3), \
          "+v"(AV_), "+v"(AC_), "+v"(AX_), "+v"(AY_), "+v"(AZ_) \
        : "v"(S), "v"(G2G), "v"(G01)); \
} while (0)

constexpr int NW    = 16;                  // waves per block
constexpr int MHALF = M_LAND / 2;          // 1024 landmarks per block
constexpr int SLICE = MHALF / NW;          // 64 landmarks per wave
constexpr int QPB   = 128;                 // queries per block

// ================= main partials kernel =================
__global__ __launch_bounds__(1024, 8)
void poisson_part_kernel(const float* __restrict__ xq,
                         const float* __restrict__ xl,
                         const float* __restrict__ gl,
                         float* __restrict__ ws)
{
    __shared__ float4 pack[MHALF];         // 16 KB
    __shared__ float4 gpack[MHALF];        // 16 KB
    __shared__ float  part[NW][QPB][5];    // 40 KB   (total 72 KB)

    const int tid  = threadIdx.x;
    const int qblk = blockIdx.x >> 1;      // 0..255
    const int ms   = blockIdx.x & 1;       // M-half

    // ---- stage this block's 1024 landmarks (1 per thread) ----
    {
        const int jg = ms * MHALF + tid;
        float l0 = xl[3*jg], l1 = xl[3*jg+1], l2 = xl[3*jg+2], g = gl[jg];
        float n2 = l0*l0 + l1*l1 + l2*l2 + EPS2;
        pack[tid]  = make_float4(-2.0f*l0, -2.0f*l1, -2.0f*l2, n2);
        gpack[tid] = make_float4(-2.0f*g*l0, -2.0f*g*l1, -2.0f*g*l2, g);
    }

    const int lane  = tid & 63;
    const int w     = tid >> 6;
    const int qbase = qblk * QPB;
    const int qa    = qbase + lane;
    const int qb    = qbase + 64 + lane;

    const float a0 = xq[3*qa], a1 = xq[3*qa+1], a2 = xq[3*qa+2];
    const float b0 = xq[3*qb], b1 = xq[3*qb+1], b2 = xq[3*qb+2];
    f32x2 Q0 = {a0, b0}, Q1 = {a1, b1}, Q2 = {a2, b2};
    f32x2 QE = {a0*a0 + a1*a1 + a2*a2, b0*b0 + b1*b1 + b2*b2};
    f32x2 AV = {0,0}, AC = {0,0}, AX = {0,0}, AY = {0,0}, AZ = {0,0};

    __syncthreads();

    const int base = w * SLICE;
#pragma unroll 2
    for (int i = 0; i < SLICE; ++i) {
        const float4 p  = pack[base + i];   // broadcast ds_read_b128
        const float4 gp = gpack[base + i];  // broadcast ds_read_b128
        f32x2 P01 = {p.x,  p.y};
        f32x2 P2W = {p.z,  p.w};
        f32x2 G01 = {gp.x, gp.y};
        f32x2 G2G = {gp.z, gp.w};
        PAIR_COMPUTE(Q0, Q1, Q2, QE, AV, AC, AX, AY, AZ);
    }

    // ---- per-(wave, query) partials ----
    part[w][lane][0] = AV.x;  part[w][lane][1] = AC.x;
    part[w][lane][2] = AX.x;  part[w][lane][3] = AY.x;  part[w][lane][4] = AZ.x;
    part[w][lane+64][0] = AV.y;  part[w][lane+64][1] = AC.y;
    part[w][lane+64][2] = AX.y;  part[w][lane+64][3] = AY.y;  part[w][lane+64][4] = AZ.y;

    __syncthreads();

    // ---- reduce 16 waves, write 640 block-partials (comp-major) ----
    if (tid < 640) {
        const int comp = tid >> 7;         // 0..4
        const int qloc = tid & 127;
        float acc = 0.f;
        #pragma unroll
        for (int ww = 0; ww < NW; ++ww) acc += part[ww][qloc][comp];
        ws[(size_t)blockIdx.x * 640 + tid] = acc;
    }
}

// ================= combine kernel: 2-way, fixed order =================
__global__ __launch_bounds__(512)
void poisson_combine_kernel(const float* __restrict__ ws,
                            const float* __restrict__ xq,
                            float* __restrict__ out, int B)
{
    const int gid  = blockIdx.x * 512 + threadIdx.x;   // 0..131071
    const int q    = gid >> 2;
    const int cmp  = gid & 3;
    const int qblk = q >> 7;
    const int qloc = q & 127;
    const float* wbase = ws + (size_t)qblk * 2 * 640;

    if (cmp == 0) {
        float s = wbase[qloc] + wbase[640 + qloc];
        out[q] = s * (INV_4PI / (float)M_LAND);
    } else {
        float sc = wbase[128 + qloc]            + wbase[640 + 128 + qloc];
        float sy = wbase[(1+cmp)*128 + qloc]    + wbase[640 + (1+cmp)*128 + qloc];
        const float qc = xq[3*q + (cmp-1)];
        // grad_c = -inv4pi/M * (q_c*Σc + 0.5*Σ c*(-2y_c))
        out[B + 3*q + (cmp-1)] =
            (-INV_4PI / (float)M_LAND) * fmaf(qc, sc, 0.5f * sy);
    }
}

// ======== fallback: R4 kernel verbatim (silicon-proven, 26.9us) ========
constexpr int NW_F  = 16;
constexpr int SL_F  = M_LAND / NW_F;
constexpr int QPB_F = 128;

__global__ __launch_bounds__(1024, 4)
void poisson_pk_kernel(const float* __restrict__ xq,
                       const float* __restrict__ xl,
                       const float* __restrict__ gl,
                       float* __restrict__ out, int B)
{
    __shared__ float4 pack[M_LAND];
    __shared__ float4 gpack[M_LAND];
    __shared__ float  part[NW_F][QPB_F][5];

    const int tid = threadIdx.x;
    for (int j = tid; j < M_LAND; j += 1024) {
        float l0 = xl[3*j], l1 = xl[3*j+1], l2 = xl[3*j+2], g = gl[j];
        float n2 = l0*l0 + l1*l1 + l2*l2 + EPS2;
        pack[j]  = make_float4(-2.0f*l0, -2.0f*l1, -2.0f*l2, n2);
        gpack[j] = make_float4(-2.0f*g*l0, -2.0f*g*l1, -2.0f*g*l2, g);
    }
    const int lane = tid & 63, w = tid >> 6;
    const int qbase = blockIdx.x * QPB_F;
    const int qa = qbase + lane, qb = qbase + 64 + lane;
    const float a0 = xq[3*qa], a1 = xq[3*qa+1], a2 = xq[3*qa+2];
    const float b0 = xq[3*qb], b1 = xq[3*qb+1], b2 = xq[3*qb+2];
    f32x2 Q0 = {a0, b0}, Q1 = {a1, b1}, Q2 = {a2, b2};
    f32x2 QE = {a0*a0 + a1*a1 + a2*a2, b0*b0 + b1*b1 + b2*b2};
    f32x2 AV = {0,0}, AC = {0,0}, AX = {0,0}, AY = {0,0}, AZ = {0,0};
    __syncthreads();

    const int base = w * SL_F;
#pragma unroll 8
    for (int i = 0; i < SL_F; ++i) {
        const float4 p  = pack[base + i];
        const float4 gp = gpack[base + i];
        f32x2 P01 = {p.x,  p.y};
        f32x2 P2W = {p.z,  p.w};
        f32x2 G01 = {gp.x, gp.y};
        f32x2 G2G = {gp.z, gp.w};
        PAIR_COMPUTE(Q0, Q1, Q2, QE, AV, AC, AX, AY, AZ);
    }
    part[w][lane][0] = AV.x;  part[w][lane][1] = AC.x;
    part[w][lane][2] = AX.x;  part[w][lane][3] = AY.x;  part[w][lane][4] = AZ.x;
    part[w][lane+64][0] = AV.y;  part[w][lane+64][1] = AC.y;
    part[w][lane+64][2] = AX.y;  part[w][lane+64][3] = AY.y;  part[w][lane+64][4] = AZ.y;
    __syncthreads();
    if (tid < 512) {
        const int q = tid >> 2, cmp = tid & 3, qg = qbase + q;
        if (cmp == 0) {
            float s = 0.f;
            #pragma unroll
            for (int ww = 0; ww < NW_F; ++ww) s += part[ww][q][0];
            out[qg] = s * (INV_4PI / (float)M_LAND);
        } else {
            float sc = 0.f, sy = 0.f;
            #pragma unroll
            for (int ww = 0; ww < NW_F; ++ww) {
                sc += part[ww][q][1];
                sy += part[ww][q][1 + cmp];
            }
            const float qc = xq[3*qg + (cmp-1)];
            out[B + 3*qg + (cmp-1)] =
                (-INV_4PI / (float)M_LAND) * fmaf(qc, sc, 0.5f * sy);
        }
    }
}

extern "C" void kernel_launch(void* const* d_in, const int* in_sizes, int n_in,
                              void* d_out, int out_size, void* d_ws, size_t ws_size,
                              hipStream_t stream)
{
    const float* xq = (const float*)d_in[0];   // (B,3)
    const float* xl = (const float*)d_in[1];   // (M,3)
    const float* gl = (const float*)d_in[2];   // (M,)
    float* out = (float*)d_out;

    const int B = in_sizes[0] / 3;             // 32768

    const size_t need = (size_t)512 * 640 * sizeof(float);   // 1.31 MB
    if (ws_size >= need && (B % QPB) == 0) {
        float* ws = (float*)d_ws;
        poisson_part_kernel<<<(B / QPB) * 2, 1024, 0, stream>>>(xq, xl, gl, ws);
        poisson_combine_kernel<<<(B * 4) / 512, 512, 0, stream>>>(ws, xq, out, B);
    } else {
        poisson_pk_kernel<<<B / QPB_F, 1024, 0, stream>>>(xq, xl, gl, out, B);
    }
}